// Round 3
// baseline (412.647 us; speedup 1.0000x reference)
//
#include <hip/hip_runtime.h>

// Problem constants (B,N,M,D) = (16,1024,4096,256), all fp32.
constexpr int B_ = 16, N_ = 1024, M_ = 4096, D_ = 256;
constexpr int ROWS = B_ * N_;      // 16384 query rows
constexpr int BR = 128;            // rows per block
constexpr int BC = 128;            // cols per tile
constexpr int KC = 16;             // K chunk
constexpr int CS = 8;              // column splits
constexpr int CPS = M_ / CS;       // cols per split = 512
constexpr int LDP = 132;           // padded LDS leading dim

// ---------------------------------------------------------------------------
// Kernel 1: row sum-of-squares replicating numpy pairwise_sum bit-exactly for
// n=256 contiguous fp32:  S = P(a[0:128]) + P(a[128:256]), where
// P(block) = ((r0+r1)+(r2+r3)) + ((r4+r5)+(r6+r7)),
// r_j = fl(a[j]^2) + fl(a[j+8]^2) + ... sequential (16 terms, stride 8).
// Squares rounded separately from adds (no FMA) -> __fmul_rn/__fadd_rn.
// 16 lanes per row: lane l = b*8+j handles accumulator r_j of block b.
// Covers both esq (ROWS rows of E) and tsq (M rows of T).
// ---------------------------------------------------------------------------
__global__ void rowsq_kernel(const float* __restrict__ E, const float* __restrict__ T,
                             float* __restrict__ esq, float* __restrict__ tsq) {
    int gt = blockIdx.x * blockDim.x + threadIdx.x;
    int row = gt >> 4;
    int l = gt & 15;
    if (row >= ROWS + M_) return;
    const float* src = (row < ROWS) ? (E + (size_t)row * D_)
                                    : (T + (size_t)(row - ROWS) * D_);
    const float* p = src + (l >> 3) * 128 + (l & 7);
    float r = __fmul_rn(p[0], p[0]);
    #pragma unroll
    for (int i = 1; i < 16; i++) {
        float x = p[8 * i];
        r = __fadd_rn(r, __fmul_rn(x, x));
    }
    // ((r0+r1)+(r2+r3))+((r4+r5)+(r6+r7)) per 8-lane block, then b0+b1.
    float u = __fadd_rn(r, __shfl_xor(r, 1, 64));
    float v = __fadd_rn(u, __shfl_xor(u, 2, 64));
    float w = __fadd_rn(v, __shfl_xor(v, 4, 64));
    float s = __fadd_rn(w, __shfl_xor(w, 8, 64));
    if (l == 0) {
        if (row < ROWS) esq[row] = s;
        else            tsq[row - ROWS] = s;
    }
}

// ---------------------------------------------------------------------------
// Kernel 2: fused GEMM (cross = E . T^T) + running argmin of the reference's
// fp32-quantized distance d2 = fl(fl(e_sq - 2*cross) + t_sq).
// argmax(logits) == argmin(d2) with min-index ties (np.argmax keeps first).
// Cross accumulation order is free: |delta| ~1e-8 << ulp(256) ~ 3e-5.
// Block: 256 threads = 16(ty) x 16(tx), 8x8 register tile -> 128x128 tile.
// ---------------------------------------------------------------------------
__global__ __launch_bounds__(256) void score_kernel(
    const float* __restrict__ E, const float* __restrict__ T,
    const float* __restrict__ esq, const float* __restrict__ tsq,
    float2* __restrict__ part) {
    __shared__ float Es[KC][LDP];
    __shared__ float Ts[KC][LDP];
    const int tid = threadIdx.x;
    const int tx = tid & 15;
    const int ty = tid >> 4;
    const int row0 = blockIdx.x * BR;
    const int cs = blockIdx.y;

    float best[8];
    int   bidx[8];
    float er[8];
    #pragma unroll
    for (int r = 0; r < 8; r++) {
        best[r] = 3.4e38f; bidx[r] = 0;
        er[r] = esq[row0 + ty * 8 + r];
    }

    const int ldr = tid >> 2;        // 0..63
    const int ldk = (tid & 3) * 4;   // 0,4,8,12

    for (int ct = 0; ct < CPS / BC; ++ct) {
        const int col0 = cs * CPS + ct * BC;
        float acc[8][8];
        #pragma unroll
        for (int r = 0; r < 8; r++)
            #pragma unroll
            for (int c = 0; c < 8; c++) acc[r][c] = 0.f;

        for (int k0 = 0; k0 < D_; k0 += KC) {
            __syncthreads();
            float4 a0 = *reinterpret_cast<const float4*>(E + (size_t)(row0 + ldr     ) * D_ + k0 + ldk);
            float4 a1 = *reinterpret_cast<const float4*>(E + (size_t)(row0 + ldr + 64) * D_ + k0 + ldk);
            float4 b0 = *reinterpret_cast<const float4*>(T + (size_t)(col0 + ldr     ) * D_ + k0 + ldk);
            float4 b1 = *reinterpret_cast<const float4*>(T + (size_t)(col0 + ldr + 64) * D_ + k0 + ldk);
            Es[ldk + 0][ldr] = a0.x; Es[ldk + 1][ldr] = a0.y; Es[ldk + 2][ldr] = a0.z; Es[ldk + 3][ldr] = a0.w;
            Es[ldk + 0][ldr + 64] = a1.x; Es[ldk + 1][ldr + 64] = a1.y; Es[ldk + 2][ldr + 64] = a1.z; Es[ldk + 3][ldr + 64] = a1.w;
            Ts[ldk + 0][ldr] = b0.x; Ts[ldk + 1][ldr] = b0.y; Ts[ldk + 2][ldr] = b0.z; Ts[ldk + 3][ldr] = b0.w;
            Ts[ldk + 0][ldr + 64] = b1.x; Ts[ldk + 1][ldr + 64] = b1.y; Ts[ldk + 2][ldr + 64] = b1.z; Ts[ldk + 3][ldr + 64] = b1.w;
            __syncthreads();
            #pragma unroll
            for (int k = 0; k < KC; k++) {
                float e[8], t[8];
                *reinterpret_cast<float4*>(&e[0]) = *reinterpret_cast<const float4*>(&Es[k][ty * 8]);
                *reinterpret_cast<float4*>(&e[4]) = *reinterpret_cast<const float4*>(&Es[k][ty * 8 + 4]);
                *reinterpret_cast<float4*>(&t[0]) = *reinterpret_cast<const float4*>(&Ts[k][tx * 4]);
                *reinterpret_cast<float4*>(&t[4]) = *reinterpret_cast<const float4*>(&Ts[k][64 + tx * 4]);
                #pragma unroll
                for (int r = 0; r < 8; r++)
                    #pragma unroll
                    for (int c = 0; c < 8; c++)
                        acc[r][c] = fmaf(e[r], t[c], acc[r][c]);
            }
        }
        // Epilogue: d2 = fl(fl(esq - 2*cross) + tsq); running argmin.
        // Cols ascend within the thread; strict '<' keeps smallest index.
        #pragma unroll
        for (int g = 0; g < 2; g++)
            #pragma unroll
            for (int c = 0; c < 4; c++) {
                const int col = col0 + g * 64 + tx * 4 + c;
                const float tc = tsq[col];
                #pragma unroll
                for (int r = 0; r < 8; r++) {
                    const float d1 = __fsub_rn(er[r], __fmul_rn(2.0f, acc[r][g * 4 + c]));
                    const float d2 = __fadd_rn(d1, tc);
                    if (d2 < best[r]) { best[r] = d2; bidx[r] = col; }
                }
            }
    }

    // Reduce across the 16 tx lanes of each ty group; min value, min index on tie.
    #pragma unroll
    for (int r = 0; r < 8; r++) {
        float v = best[r]; int i = bidx[r];
        #pragma unroll
        for (int off = 1; off < 16; off <<= 1) {
            float ov = __shfl_xor(v, off, 64);
            int   oi = __shfl_xor(i, off, 64);
            if (ov < v || (ov == v && oi < i)) { v = ov; i = oi; }
        }
        if (tx == 0)
            part[(size_t)(row0 + ty * 8 + r) * CS + cs] = make_float2(v, __int_as_float(i));
    }
}

// ---------------------------------------------------------------------------
// Kernel 3: reduce CS partials per row (min value, min index on ties), gather
// quant = templat[idx] (bitwise copy), write zidx as float. One wave per row.
// ---------------------------------------------------------------------------
__global__ void gather_kernel(const float* __restrict__ T, const float2* __restrict__ part,
                              float* __restrict__ quant, float* __restrict__ zout) {
    int gt = blockIdx.x * blockDim.x + threadIdx.x;
    int w = gt >> 6, lane = gt & 63;
    if (w >= ROWS) return;
    float2 p = part[(size_t)w * CS];
    float v = p.x; int idx = __float_as_int(p.y);
    #pragma unroll
    for (int c = 1; c < CS; c++) {
        float2 q = part[(size_t)w * CS + c];
        int qi = __float_as_int(q.y);
        if (q.x < v || (q.x == v && qi < idx)) { v = q.x; idx = qi; }
    }
    float4 t = *reinterpret_cast<const float4*>(T + (size_t)idx * D_ + lane * 4);
    *reinterpret_cast<float4*>(quant + (size_t)w * D_ + lane * 4) = t;
    if (lane == 0) zout[w] = (float)idx;
}

// ---------------------------------------------------------------------------
extern "C" void kernel_launch(void* const* d_in, const int* in_sizes, int n_in,
                              void* d_out, int out_size, void* d_ws, size_t ws_size,
                              hipStream_t stream) {
    const float* E = (const float*)d_in[0];   // encode  (B,N,D)
    const float* T = (const float*)d_in[1];   // templat (M,D)
    float* quant = (float*)d_out;                        // (B,N,D) fp32
    float* zout  = quant + (size_t)ROWS * D_;            // (B,N) idx as fp32
    float* esq   = (float*)d_ws;                         // ROWS floats
    float* tsq   = esq + ROWS;                           // M floats
    float2* part = (float2*)(tsq + M_);                  // ROWS*CS float2

    hipLaunchKernelGGL(rowsq_kernel, dim3((ROWS + M_) * 16 / 256), dim3(256), 0, stream, E, T, esq, tsq);
    hipLaunchKernelGGL(score_kernel, dim3(ROWS / BR, CS), dim3(256), 0, stream, E, T, esq, tsq, part);
    hipLaunchKernelGGL(gather_kernel, dim3(ROWS * 64 / 256), dim3(256), 0, stream, T, part, quant, zout);
}